// Round 1
// 182.875 us; speedup vs baseline: 1.0882x; 1.0882x over previous
//
#include <hip/hip_runtime.h>

typedef _Float16 half8 __attribute__((ext_vector_type(8)));
typedef _Float16 half4 __attribute__((ext_vector_type(4)));
typedef float f32x4 __attribute__((ext_vector_type(4)));

#define MFMA16(a, b, c) __builtin_amdgcn_mfma_f32_16x16x32_f16((a), (b), (c), 0, 0, 0)
#define MFMA16K16(a, b, c) __builtin_amdgcn_mfma_f32_16x16x16f16((a), (b), (c), 0, 0, 0)
#define EXP2F(x) __builtin_amdgcn_exp2f(x)

#define GLOBAL_LOAD_LDS16(gptr, lptr)                                        \
    __builtin_amdgcn_global_load_lds(                                        \
        (const __attribute__((address_space(1))) void*)(gptr),               \
        (__attribute__((address_space(3))) void*)(lptr), 16, 0, 0)

// Q is pre-scaled by softmax_scale * log2(e) in the qkv epilogue.
#define QSCALE 0.18033688f  // 0.125 * log2(e)

// ---------------- fused prep: cast x + transpose-cast both weights ----------------

__global__ __launch_bounds__(256) void prep_kernel(const float* __restrict__ x,
                                                   const float* __restrict__ Wqkv,
                                                   const float* __restrict__ Wproj,
                                                   _Float16* __restrict__ Xh,
                                                   _Float16* __restrict__ Wqt,
                                                   _Float16* __restrict__ Wpt) {
    const int bid = blockIdx.x;
    const int tid = threadIdx.x;
    if (bid < 4096) {
        int i = bid * 1024 + tid * 4;
        float4 v = *(const float4*)(x + i);
        half4 h = {(_Float16)v.x, (_Float16)v.y, (_Float16)v.z, (_Float16)v.w};
        *(half4*)(Xh + i) = h;
        return;
    }
    __shared__ _Float16 tile[32][33];
    const float* W;
    _Float16* Wt;
    int n0, k0, N;
    if (bid < 7168) {
        int t = bid - 4096;
        W = Wqkv; Wt = Wqt; N = 3072;
        n0 = (t % 96) * 32; k0 = (t / 96) * 32;
    } else {
        int t = bid - 7168;
        W = Wproj; Wt = Wpt; N = 1024;
        n0 = (t & 31) * 32; k0 = (t >> 5) * 32;
    }
    int c = tid & 31, r4 = tid >> 5;
    for (int i = 0; i < 4; i++) {
        int r = r4 + i * 8;
        tile[r][c] = (_Float16)W[(k0 + r) * N + n0 + c];
    }
    __syncthreads();
    for (int i = 0; i < 4; i++) {
        int r = r4 + i * 8;  // n within tile
        Wt[(n0 + r) * 1024 + k0 + c] = tile[c][r];
    }
}

// ---------------- QKV GEMM: 256x256-tile 8-phase counted-vmcnt (T2+T3+T4+T5) ----------------
// 8 waves (2M x 4N), BK=64, double-buffered 128 KB LDS, K-split half-tile staging.
// Per-iter (2 K-tiles): 8 phases of {4/8 ds_read_b128; 1 half-tile GLL stage;
// barrier; 16 MFMA (setprio-wrapped); [vmcnt(4) @ p4/p8]; barrier}.
// Steady-state ledger: stage runs 1.5 tiles ahead; vmcnt never drains to 0 in-loop.
// Grid 192 = 16m x 12n tiles, XCD-chunked (2 m-strips/XCD -> 1 MB A L2-resident).

#define SCHED0() __builtin_amdgcn_sched_barrier(0)
#define BARRIER() do { SCHED0(); asm volatile("" ::: "memory");            \
                       __builtin_amdgcn_s_barrier();                        \
                       asm volatile("" ::: "memory"); SCHED0(); } while (0)
#define WAITV(N) asm volatile("s_waitcnt vmcnt(" #N ")" ::: "memory")

// LDS half-offset (in _Float16 units) for logical (row, quad-colslot) within a
// 256x32 kk-half. 2 rows per 128B LDS line, 8 slot swizzle -> 2-way max (free).
#define LOFF(ROW, Q) ((((ROW) >> 1) * 64) + \
    ((((((ROW) & 1) << 2) | (Q)) ^ (((ROW) >> 1) & 7)) * 8))

__global__ __launch_bounds__(512) void gemm_qkv(const _Float16* __restrict__ A,
                                                const _Float16* __restrict__ Bt,
                                                const float* __restrict__ bias,
                                                _Float16* __restrict__ Qo,
                                                _Float16* __restrict__ Ko,
                                                _Float16* __restrict__ Vto) {
    __shared__ _Float16 L[65536];  // [buf2][op2][kk2][8192 halfs] = 128 KB
    const int tid = threadIdx.x;
    const int lin = blockIdx.x;
    const int xcd = lin & 7, slot = lin >> 3;      // slot 0..23
    const int m0 = (xcd * 2 + slot / 12) * 256;    // 16 m-tiles
    const int n0 = (slot % 12) * 256;              // 12 n-tiles
    const int wave = tid >> 6, lane = tid & 63;
    const int wm = wave >> 2, wn = wave & 3;       // 2M x 4N waves
    const int quad = lane >> 4, l15 = lane & 15;

    // staging: linear GLL dest (lane*16B), pre-swizzled global source
    const int s8 = (tid & 7) ^ ((tid >> 3) & 7);   // logical 16B-slot (0..7)
    const int srow = (tid >> 3) * 2 + (s8 >> 2);   // logical row (round 0)
    const int scol = (s8 & 3) * 8;                 // logical col within kk-half
    const _Float16* Asrc = A + (size_t)(m0 + srow) * 1024 + scol;
    const _Float16* Bsrc = Bt + (size_t)(n0 + srow) * 1024 + scol;
    _Float16* Ldst = L + tid * 8;

#define STG(OP, KK, KT) do {                                                  \
    const _Float16* _g = ((OP) ? Bsrc : Asrc) + ((KT) & 15) * 64 + (KK) * 32; \
    _Float16* _l = Ldst + ((KT) & 1) * 32768 + (OP) * 16384 + (KK) * 8192;    \
    GLOBAL_LOAD_LDS16(_g, _l);                                                \
    GLOBAL_LOAD_LDS16(_g + 128 * 1024, _l + 4096);                            \
} while (0)

    const int arow = wm * 128 + l15;   // + MH*64 + fi*16
    const int brow = wn * 64 + l15;    // + nf*16

    f32x4 acc[8][4] = {};
    half8 af[4], bf[4];

#define PHASE(BUF, KK, MH, RDB, SOP, SKK, SKT, W4) do {                        \
    const _Float16* _ab = L + (BUF) * 32768 + (KK) * 8192;                     \
    const _Float16* _bb = _ab + 16384;                                         \
    if (RDB) {                                                                 \
        _Pragma("unroll") for (int nf = 0; nf < 4; nf++)                       \
            bf[nf] = *(const half8*)(_bb + LOFF(brow + nf * 16, quad));        \
    }                                                                          \
    _Pragma("unroll") for (int fi = 0; fi < 4; fi++)                           \
        af[fi] = *(const half8*)(_ab + LOFF(arow + (MH) * 64 + fi * 16, quad));\
    STG(SOP, SKK, SKT);                                                        \
    BARRIER();                                                                 \
    __builtin_amdgcn_s_setprio(1);                                             \
    _Pragma("unroll") for (int fi = 0; fi < 4; fi++)                           \
        _Pragma("unroll") for (int nf = 0; nf < 4; nf++)                       \
            acc[(MH) * 4 + fi][nf] = MFMA16(af[fi], bf[nf],                    \
                                            acc[(MH) * 4 + fi][nf]);           \
    __builtin_amdgcn_s_setprio(0);                                             \
    if (W4) { WAITV(4); }                                                      \
    BARRIER();                                                                 \
} while (0)

    // prologue: tile0 complete + tile1 lo-halves in flight
    STG(0, 0, 0); STG(1, 0, 0); STG(0, 1, 0); STG(1, 1, 0);
    STG(0, 0, 1); STG(1, 0, 1);
    WAITV(4);           // tile0's 8 loads done; tile1 lo (4 loads) in flight
    BARRIER();

    for (int i = 0; i < 8; ++i) {
        const int ta = 2 * i, tb = 2 * i + 1;
        // phase: (buf, kk, mh, readB, stage-op, stage-kk, stage-tile, wait)
        PHASE(0, 0, 0, 1, 0, 1, tb,     0);  // p1: +stage A-hi(t+1)
        PHASE(0, 0, 1, 0, 1, 1, tb,     0);  // p2: +stage B-hi(t+1)
        PHASE(0, 1, 0, 1, 0, 0, ta + 2, 0);  // p3: +stage A-lo(t+2)
        PHASE(0, 1, 1, 0, 1, 0, ta + 2, 1);  // p4: +stage B-lo(t+2); vmcnt(4)
        PHASE(1, 0, 0, 1, 0, 1, ta + 2, 0);  // p5: +stage A-hi(t+2)
        PHASE(1, 0, 1, 0, 1, 1, ta + 2, 0);  // p6: +stage B-hi(t+2)
        PHASE(1, 1, 0, 1, 0, 0, tb + 2, 0);  // p7: +stage A-lo(t+3)
        PHASE(1, 1, 1, 0, 1, 0, tb + 2, 1);  // p8: +stage B-lo(t+3); vmcnt(4)
    }
    WAITV(0);  // drain trailing (wrapped) stages before epilogue / endpgm

    // epilogue: scatter to Q (scaled) / K / Vt. which is block-uniform.
    const int which = n0 >> 10;
    const int hh = ((n0 + wn * 64) & 1023) >> 6;  // head idx (wave-uniform)
    float bv[4];
    const int gnb = n0 + wn * 64;
#pragma unroll
    for (int nf = 0; nf < 4; nf++) bv[nf] = bias[gnb + nf * 16 + l15];

#pragma unroll
    for (int mf = 0; mf < 8; mf++) {
        const int gm0 = m0 + wm * 128 + mf * 16 + quad * 4;
        const int b = gm0 >> 11, t0 = gm0 & 2047;
        const int bh = b * 16 + hh;
#pragma unroll
        for (int nf = 0; nf < 4; nf++) {
            const int dh = nf * 16 + l15;
            if (which == 2) {
                half4 hv;
#pragma unroll
                for (int r = 0; r < 4; r++)
                    hv[r] = (_Float16)(acc[mf][nf][r] + bv[nf]);
                *(half4*)(&Vto[(size_t)(bh * 64 + dh) * 2048 + t0]) = hv;
            } else if (which == 0) {
#pragma unroll
                for (int r = 0; r < 4; r++)
                    Qo[((size_t)bh * 2048 + t0 + r) * 64 + dh] =
                        (_Float16)((acc[mf][nf][r] + bv[nf]) * QSCALE);
            } else {
#pragma unroll
                for (int r = 0; r < 4; r++)
                    Ko[((size_t)bh * 2048 + t0 + r) * 64 + dh] =
                        (_Float16)(acc[mf][nf][r] + bv[nf]);
            }
        }
    }
#undef PHASE
#undef STG
}

// ---------------- flash attention, transpose-S (best: R7 config) ----------------
// grid (32 bh, 16 qt): 128 q per block, 32 q per wave (two 16-q groups).
// Ks[128][64] XOR-swizzled; Vs[64][132] stride 66 dw == 2 mod 32 (conflict-free).
// 32.7 KB LDS. bh on x -> per-XCD K/V 2 MB L2-resident.

__global__ __launch_bounds__(256) void attn_kernel(const _Float16* __restrict__ Qg,
                                                   const _Float16* __restrict__ Kg,
                                                   const _Float16* __restrict__ Vtg,
                                                   _Float16* __restrict__ AO) {
    __shared__ _Float16 Ks[128][64];
    __shared__ _Float16 Vs[64][132];

    const int tid = threadIdx.x;
    const int bh = blockIdx.x;
    const int q0 = blockIdx.y * 128;
    const int b = bh >> 4, h = bh & 15;
    const int wave = tid >> 6, lane = tid & 63;
    const int quad = lane >> 4, l15 = lane & 15;
    const int akey = l15 & 7;

    half8 qf[2][2];
    for (int g = 0; g < 2; g++) {
        const int qrow = q0 + wave * 32 + g * 16 + l15;
        for (int kk = 0; kk < 2; kk++)
            qf[g][kk] = *(const half8*)(&Qg[(bh * 2048 + qrow) * 64 + kk * 32 + quad * 8]);
    }

    const int srow = tid >> 3;
    const int sgcol = (tid & 7) * 8;
    const int sscol = (((tid & 7) ^ (srow & 7))) * 8;
    const int vrow = tid >> 4;
    const int vgcol = (tid & 15) * 8;

    const _Float16* Kbase = Kg + (size_t)bh * 2048 * 64;
    const _Float16* Vbase = Vtg + (size_t)bh * 64 * 2048;

    half8 kreg[4], vreg[4];
    for (int i = 0; i < 4; i++)
        kreg[i] = *(const half8*)(Kbase + (srow + i * 32) * 64 + sgcol);
    for (int i = 0; i < 4; i++)
        vreg[i] = *(const half8*)(Vbase + (vrow + i * 16) * 2048 + vgcol);

    float lsum[2] = {0.f, 0.f};
    f32x4 oacc[2][4] = {};

    for (int kt = 0; kt < 16; kt++) {
        __syncthreads();
        for (int i = 0; i < 4; i++)
            *(half8*)(&Ks[srow + i * 32][sscol]) = kreg[i];
        for (int i = 0; i < 4; i++)
            *(half8*)(&Vs[vrow + i * 16][vgcol]) = vreg[i];
        __syncthreads();
        if (kt < 15) {
            const int kb = (kt + 1) * 128;
            for (int i = 0; i < 4; i++)
                kreg[i] = *(const half8*)(Kbase + (kb + srow + i * 32) * 64 + sgcol);
            for (int i = 0; i < 4; i++)
                vreg[i] = *(const half8*)(Vbase + (vrow + i * 16) * 2048 + kb + vgcol);
        }

#pragma unroll
        for (int ni = 0; ni < 8; ni++) {
            half8 ka = *(const half8*)(&Ks[ni * 16 + l15][(quad ^ akey) * 8]);
            half8 kb2 = *(const half8*)(&Ks[ni * 16 + l15][((quad + 4) ^ akey) * 8]);
            f32x4 s0 = {}, s1 = {};
            s0 = MFMA16(ka, qf[0][0], s0);
            s0 = MFMA16(kb2, qf[0][1], s0);
            s1 = MFMA16(ka, qf[1][0], s1);
            s1 = MFMA16(kb2, qf[1][1], s1);
            half4 bP0, bP1;
            float e;
            float a0 = 0.f, a1 = 0.f;
            e = EXP2F(s0[0]); a0 += e; bP0[0] = (_Float16)e;
            e = EXP2F(s0[1]); a0 += e; bP0[1] = (_Float16)e;
            e = EXP2F(s0[2]); a0 += e; bP0[2] = (_Float16)e;
            e = EXP2F(s0[3]); a0 += e; bP0[3] = (_Float16)e;
            e = EXP2F(s1[0]); a1 += e; bP1[0] = (_Float16)e;
            e = EXP2F(s1[1]); a1 += e; bP1[1] = (_Float16)e;
            e = EXP2F(s1[2]); a1 += e; bP1[2] = (_Float16)e;
            e = EXP2F(s1[3]); a1 += e; bP1[3] = (_Float16)e;
            lsum[0] += a0; lsum[1] += a1;
#pragma unroll
            for (int di = 0; di < 4; di++) {
                half4 av = *(const half4*)(&Vs[di * 16 + l15][ni * 16 + quad * 4]);
                oacc[0][di] = MFMA16K16(av, bP0, oacc[0][di]);
                oacc[1][di] = MFMA16K16(av, bP1, oacc[1][di]);
            }
        }
    }

    for (int g = 0; g < 2; g++) {
        float s = lsum[g];
        s += __shfl_xor(s, 16, 64);
        s += __shfl_xor(s, 32, 64);
        float inv = 1.f / s;
        const int qrow = q0 + wave * 32 + g * 16 + l15;
        for (int di = 0; di < 4; di++) {
            half4 hv;
            hv[0] = (_Float16)(oacc[g][di][0] * inv);
            hv[1] = (_Float16)(oacc[g][di][1] * inv);
            hv[2] = (_Float16)(oacc[g][di][2] * inv);
            hv[3] = (_Float16)(oacc[g][di][3] * inv);
            *(half4*)(&AO[(size_t)(b * 2048 + qrow) * 1024 + h * 64 + di * 16 + quad * 4]) = hv;
        }
    }
}

// ---------------- proj GEMM: out[4096,1024] = AO @ Wp + bp (fp32 out) ----------------
// R9 structure: 64x128 tile, GLL staging, XCD remap (AO-strip 1MB + Wpt 2MB
// per XCD, both L2-resident).

__global__ __launch_bounds__(256) void gemm_proj(const _Float16* __restrict__ A,
                                                 const _Float16* __restrict__ Bt,
                                                 const float* __restrict__ bias,
                                                 float* __restrict__ out) {
    __shared__ _Float16 As[64][64];    //  8 KB
    __shared__ _Float16 Bs[128][64];   // 16 KB
    const int tid = threadIdx.x;
    const int lin = blockIdx.x + 8 * blockIdx.y;
    const int xcd = lin & 7, slot = lin >> 3;     // slot 0..63
    const int n0 = (slot >> 3) * 128;
    const int m0 = (xcd * 8 + (slot & 7)) * 64;
    const int wave = tid >> 6, lane = tid & 63;
    const int quad = lane >> 4, l15 = lane & 15;
    const int sw = l15 & 7;
    const int ldrowA = wave * 16 + (lane >> 3);
    const int ldrowB = wave * 32 + (lane >> 3);
    const int ldslot = (lane & 7) * 8;
    const int gcolA = (((lane & 7) ^ (ldrowA & 7))) * 8;
    const int gcolB = (((lane & 7) ^ (ldrowB & 7))) * 8;

    f32x4 acc[4][2] = {};
    for (int k0 = 0; k0 < 1024; k0 += 64) {
        __syncthreads();
        for (int i = 0; i < 2; i++) {
            int r = ldrowA + i * 8;
            GLOBAL_LOAD_LDS16(&A[(size_t)(m0 + r) * 1024 + k0 + gcolA], &As[r][ldslot]);
        }
        for (int i = 0; i < 4; i++) {
            int r = ldrowB + i * 8;
            GLOBAL_LOAD_LDS16(&Bt[(size_t)(n0 + r) * 1024 + k0 + gcolB], &Bs[r][ldslot]);
        }
        __syncthreads();
        for (int kk = 0; kk < 64; kk += 32) {
            const int rcol = (((kk >> 3) + quad) ^ sw) * 8;
            half8 af[4], bf[2];
            for (int mi = 0; mi < 4; mi++)
                af[mi] = *(const half8*)(&As[mi * 16 + l15][rcol]);
            for (int ni = 0; ni < 2; ni++)
                bf[ni] = *(const half8*)(&Bs[wave * 32 + ni * 16 + l15][rcol]);
            for (int mi = 0; mi < 4; mi++)
                for (int ni = 0; ni < 2; ni++)
                    acc[mi][ni] = MFMA16(af[mi], bf[ni], acc[mi][ni]);
        }
    }
    for (int mi = 0; mi < 4; mi++)
        for (int ni = 0; ni < 2; ni++) {
            int gn = n0 + wave * 32 + ni * 16 + l15;
            float bv = bias[gn];
            for (int r = 0; r < 4; r++) {
                int gm = m0 + mi * 16 + quad * 4 + r;
                out[(size_t)gm * 1024 + gn] = acc[mi][ni][r] + bv;
            }
        }
}

// ---------------- launch ----------------

extern "C" void kernel_launch(void* const* d_in, const int* in_sizes, int n_in,
                              void* d_out, int out_size, void* d_ws, size_t ws_size,
                              hipStream_t stream) {
    const float* x     = (const float*)d_in[0];
    const float* Wqkv  = (const float*)d_in[1];
    const float* bqkv  = (const float*)d_in[2];
    const float* Wproj = (const float*)d_in[3];
    const float* bproj = (const float*)d_in[4];
    float* out = (float*)d_out;

    char* ws = (char*)d_ws;
    const size_t MB = 1024 * 1024;
    _Float16* Xh  = (_Float16*)(ws + 0 * MB);   // [4096][1024]   8 MB
    _Float16* Wqt = (_Float16*)(ws + 8 * MB);   // [3072][1024]   6 MB
    _Float16* Wpt = (_Float16*)(ws + 14 * MB);  // [1024][1024]   2 MB
    _Float16* Qg  = (_Float16*)(ws + 16 * MB);  // [32][2048][64] 8 MB (pre-scaled)
    _Float16* Kg  = (_Float16*)(ws + 24 * MB);  // [32][2048][64] 8 MB
    _Float16* Vtg = (_Float16*)(ws + 32 * MB);  // [32][64][2048] 8 MB
    _Float16* AO  = (_Float16*)(ws + 40 * MB);  // [4096][1024]   8 MB

    prep_kernel<<<8192, 256, 0, stream>>>(x, Wqkv, Wproj, Xh, Wqt, Wpt);
    gemm_qkv<<<192, 512, 0, stream>>>(Xh, Wqt, bqkv, Qg, Kg, Vtg);
    attn_kernel<<<dim3(32, 16), 256, 0, stream>>>(Qg, Kg, Vtg, AO);
    gemm_proj<<<dim3(8, 64), 256, 0, stream>>>(AO, Wpt, bproj, out);
}

// Round 2
// 176.756 us; speedup vs baseline: 1.1259x; 1.0346x over previous
//
#include <hip/hip_runtime.h>

typedef _Float16 half8 __attribute__((ext_vector_type(8)));
typedef _Float16 half4 __attribute__((ext_vector_type(4)));
typedef float f32x4 __attribute__((ext_vector_type(4)));

#define MFMA16(a, b, c) __builtin_amdgcn_mfma_f32_16x16x32_f16((a), (b), (c), 0, 0, 0)
#define MFMA16K16(a, b, c) __builtin_amdgcn_mfma_f32_16x16x16f16((a), (b), (c), 0, 0, 0)
#define EXP2F(x) __builtin_amdgcn_exp2f(x)

#define GLOBAL_LOAD_LDS16(gptr, lptr)                                        \
    __builtin_amdgcn_global_load_lds(                                        \
        (const __attribute__((address_space(1))) void*)(gptr),               \
        (__attribute__((address_space(3))) void*)(lptr), 16, 0, 0)

// Q is pre-scaled by softmax_scale * log2(e) in the qkv epilogue.
#define QSCALE 0.18033688f  // 0.125 * log2(e)

// ---------------- fused prep: cast x + transpose-cast both weights ----------------

__global__ __launch_bounds__(256) void prep_kernel(const float* __restrict__ x,
                                                   const float* __restrict__ Wqkv,
                                                   const float* __restrict__ Wproj,
                                                   _Float16* __restrict__ Xh,
                                                   _Float16* __restrict__ Wqt,
                                                   _Float16* __restrict__ Wpt) {
    const int bid = blockIdx.x;
    const int tid = threadIdx.x;
    if (bid < 4096) {
        int i = bid * 1024 + tid * 4;
        float4 v = *(const float4*)(x + i);
        half4 h = {(_Float16)v.x, (_Float16)v.y, (_Float16)v.z, (_Float16)v.w};
        *(half4*)(Xh + i) = h;
        return;
    }
    __shared__ _Float16 tile[32][33];
    const float* W;
    _Float16* Wt;
    int n0, k0, N;
    if (bid < 7168) {
        int t = bid - 4096;
        W = Wqkv; Wt = Wqt; N = 3072;
        n0 = (t % 96) * 32; k0 = (t / 96) * 32;
    } else {
        int t = bid - 7168;
        W = Wproj; Wt = Wpt; N = 1024;
        n0 = (t & 31) * 32; k0 = (t >> 5) * 32;
    }
    int c = tid & 31, r4 = tid >> 5;
    for (int i = 0; i < 4; i++) {
        int r = r4 + i * 8;
        tile[r][c] = (_Float16)W[(k0 + r) * N + n0 + c];
    }
    __syncthreads();
    for (int i = 0; i < 4; i++) {
        int r = r4 + i * 8;  // n within tile
        Wt[(n0 + r) * 1024 + k0 + c] = tile[c][r];
    }
}

// ---------------- QKV GEMM: 256x256-tile 8-phase counted-vmcnt (T2+T3+T4+T5) ----------------

#define SCHED0() __builtin_amdgcn_sched_barrier(0)
#define BARRIER() do { SCHED0(); asm volatile("" ::: "memory");            \
                       __builtin_amdgcn_s_barrier();                        \
                       asm volatile("" ::: "memory"); SCHED0(); } while (0)
#define WAITV(N) asm volatile("s_waitcnt vmcnt(" #N ")" ::: "memory")

#define LOFF(ROW, Q) ((((ROW) >> 1) * 64) + \
    ((((((ROW) & 1) << 2) | (Q)) ^ (((ROW) >> 1) & 7)) * 8))

__global__ __launch_bounds__(512) void gemm_qkv(const _Float16* __restrict__ A,
                                                const _Float16* __restrict__ Bt,
                                                const float* __restrict__ bias,
                                                _Float16* __restrict__ Qo,
                                                _Float16* __restrict__ Ko,
                                                _Float16* __restrict__ Vto) {
    __shared__ _Float16 L[65536];  // [buf2][op2][kk2][8192 halfs] = 128 KB
    const int tid = threadIdx.x;
    const int lin = blockIdx.x;
    const int xcd = lin & 7, slot = lin >> 3;      // slot 0..23
    const int m0 = (xcd * 2 + slot / 12) * 256;    // 16 m-tiles
    const int n0 = (slot % 12) * 256;              // 12 n-tiles
    const int wave = tid >> 6, lane = tid & 63;
    const int wm = wave >> 2, wn = wave & 3;       // 2M x 4N waves
    const int quad = lane >> 4, l15 = lane & 15;

    // staging: linear GLL dest (lane*16B), pre-swizzled global source
    const int s8 = (tid & 7) ^ ((tid >> 3) & 7);   // logical 16B-slot (0..7)
    const int srow = (tid >> 3) * 2 + (s8 >> 2);   // logical row (round 0)
    const int scol = (s8 & 3) * 8;                 // logical col within kk-half
    const _Float16* Asrc = A + (size_t)(m0 + srow) * 1024 + scol;
    const _Float16* Bsrc = Bt + (size_t)(n0 + srow) * 1024 + scol;
    _Float16* Ldst = L + tid * 8;

#define STG(OP, KK, KT) do {                                                  \
    const _Float16* _g = ((OP) ? Bsrc : Asrc) + ((KT) & 15) * 64 + (KK) * 32; \
    _Float16* _l = Ldst + ((KT) & 1) * 32768 + (OP) * 16384 + (KK) * 8192;    \
    GLOBAL_LOAD_LDS16(_g, _l);                                                \
    GLOBAL_LOAD_LDS16(_g + 128 * 1024, _l + 4096);                            \
} while (0)

    const int arow = wm * 128 + l15;   // + MH*64 + fi*16
    const int brow = wn * 64 + l15;    // + nf*16

    f32x4 acc[8][4] = {};
    half8 af[4], bf[4];

#define PHASE(BUF, KK, MH, RDB, SOP, SKK, SKT, W4) do {                        \
    const _Float16* _ab = L + (BUF) * 32768 + (KK) * 8192;                     \
    const _Float16* _bb = _ab + 16384;                                         \
    if (RDB) {                                                                 \
        _Pragma("unroll") for (int nf = 0; nf < 4; nf++)                       \
            bf[nf] = *(const half8*)(_bb + LOFF(brow + nf * 16, quad));        \
    }                                                                          \
    _Pragma("unroll") for (int fi = 0; fi < 4; fi++)                           \
        af[fi] = *(const half8*)(_ab + LOFF(arow + (MH) * 64 + fi * 16, quad));\
    STG(SOP, SKK, SKT);                                                        \
    BARRIER();                                                                 \
    __builtin_amdgcn_s_setprio(1);                                             \
    _Pragma("unroll") for (int fi = 0; fi < 4; fi++)                           \
        _Pragma("unroll") for (int nf = 0; nf < 4; nf++)                       \
            acc[(MH) * 4 + fi][nf] = MFMA16(af[fi], bf[nf],                    \
                                            acc[(MH) * 4 + fi][nf]);           \
    __builtin_amdgcn_s_setprio(0);                                             \
    if (W4) { WAITV(4); }                                                      \
    BARRIER();                                                                 \
} while (0)

    // prologue: tile0 complete + tile1 lo-halves in flight
    STG(0, 0, 0); STG(1, 0, 0); STG(0, 1, 0); STG(1, 1, 0);
    STG(0, 0, 1); STG(1, 0, 1);
    WAITV(4);           // tile0's 8 loads done; tile1 lo (4 loads) in flight
    BARRIER();

    for (int i = 0; i < 8; ++i) {
        const int ta = 2 * i, tb = 2 * i + 1;
        PHASE(0, 0, 0, 1, 0, 1, tb,     0);  // p1: +stage A-hi(t+1)
        PHASE(0, 0, 1, 0, 1, 1, tb,     0);  // p2: +stage B-hi(t+1)
        PHASE(0, 1, 0, 1, 0, 0, ta + 2, 0);  // p3: +stage A-lo(t+2)
        PHASE(0, 1, 1, 0, 1, 0, ta + 2, 1);  // p4: +stage B-lo(t+2); vmcnt(4)
        PHASE(1, 0, 0, 1, 0, 1, ta + 2, 0);  // p5: +stage A-hi(t+2)
        PHASE(1, 0, 1, 0, 1, 1, ta + 2, 0);  // p6: +stage B-hi(t+2)
        PHASE(1, 1, 0, 1, 0, 0, tb + 2, 0);  // p7: +stage A-lo(t+3)
        PHASE(1, 1, 1, 0, 1, 0, tb + 2, 1);  // p8: +stage B-lo(t+3); vmcnt(4)
    }
    WAITV(0);  // drain trailing (wrapped) stages before epilogue / endpgm

    // epilogue: scatter to Q (scaled) / K / Vt. which is block-uniform.
    const int which = n0 >> 10;
    const int hh = ((n0 + wn * 64) & 1023) >> 6;  // head idx (wave-uniform)
    float bv[4];
    const int gnb = n0 + wn * 64;
#pragma unroll
    for (int nf = 0; nf < 4; nf++) bv[nf] = bias[gnb + nf * 16 + l15];

#pragma unroll
    for (int mf = 0; mf < 8; mf++) {
        const int gm0 = m0 + wm * 128 + mf * 16 + quad * 4;
        const int b = gm0 >> 11, t0 = gm0 & 2047;
        const int bh = b * 16 + hh;
#pragma unroll
        for (int nf = 0; nf < 4; nf++) {
            const int dh = nf * 16 + l15;
            if (which == 2) {
                half4 hv;
#pragma unroll
                for (int r = 0; r < 4; r++)
                    hv[r] = (_Float16)(acc[mf][nf][r] + bv[nf]);
                *(half4*)(&Vto[(size_t)(bh * 64 + dh) * 2048 + t0]) = hv;
            } else if (which == 0) {
#pragma unroll
                for (int r = 0; r < 4; r++)
                    Qo[((size_t)bh * 2048 + t0 + r) * 64 + dh] =
                        (_Float16)((acc[mf][nf][r] + bv[nf]) * QSCALE);
            } else {
#pragma unroll
                for (int r = 0; r < 4; r++)
                    Ko[((size_t)bh * 2048 + t0 + r) * 64 + dh] =
                        (_Float16)(acc[mf][nf][r] + bv[nf]);
            }
        }
    }
#undef PHASE
#undef STG
}

// ---------------- flash attention, transpose-S, 8-wave ni-split ----------------
// grid (32 bh, 16 qt), 512 threads: 4 q-groups x 2 ni-halves. Each wave does
// 32 q x half the k-columns of each 128-k tile; O/l partials are purely
// additive (no max tracking) -> 2-pass LDS combine at the end.
// 4 waves/SIMD (vs 2) at unchanged total LDS traffic: latency-bound fix.
// Row-sums via ones-MFMA (matrix pipe has headroom; frees VALU + kills shfl).

__global__ __launch_bounds__(512, 4) void attn_kernel(const _Float16* __restrict__ Qg,
                                                      const _Float16* __restrict__ Kg,
                                                      const _Float16* __restrict__ Vtg,
                                                      _Float16* __restrict__ AO) {
    __shared__ _Float16 Ks[128][64];    // 16 KB, XOR-swizzled
    __shared__ _Float16 Vs[64][132];    // 16.5 KB, stride 66 dw

    const int tid = threadIdx.x;
    const int bh = blockIdx.x;
    const int q0 = blockIdx.y * 128;
    const int b = bh >> 4, h = bh & 15;
    const int wave = tid >> 6, lane = tid & 63;
    const int pw = wave & 3;     // q-group (32 q)
    const int kh = wave >> 2;    // ni half: 0 -> ni 0..3, 1 -> ni 4..7
    const int quad = lane >> 4, l15 = lane & 15;
    const int akey = l15 & 7;

    half8 qf[2][2];
    for (int g = 0; g < 2; g++) {
        const int qrow = q0 + pw * 32 + g * 16 + l15;
        for (int kk = 0; kk < 2; kk++)
            qf[g][kk] = *(const half8*)(&Qg[(bh * 2048 + qrow) * 64 + kk * 32 + quad * 8]);
    }

    // staging (512 threads: 2 rounds each for K and V)
    const int srow = tid >> 3;           // 0..63
    const int sc8 = tid & 7;
    const int sgcol = sc8 * 8;
    const int sscol = (sc8 ^ (srow & 7)) * 8;
    const int vrow = tid >> 4;           // 0..31
    const int vgcol = (tid & 15) * 8;

    const _Float16* Kbase = Kg + (size_t)bh * 2048 * 64;
    const _Float16* Vbase = Vtg + (size_t)bh * 64 * 2048;

    half8 kreg[2], vreg[2];
    for (int i = 0; i < 2; i++)
        kreg[i] = *(const half8*)(Kbase + (srow + i * 64) * 64 + sgcol);
    for (int i = 0; i < 2; i++)
        vreg[i] = *(const half8*)(Vbase + (vrow + i * 32) * 2048 + vgcol);

    const half4 vone = {(_Float16)1.f, (_Float16)1.f, (_Float16)1.f, (_Float16)1.f};
    f32x4 lacc[2] = {};
    f32x4 oacc[2][4] = {};

    for (int kt = 0; kt < 16; kt++) {
        __syncthreads();
        for (int i = 0; i < 2; i++)
            *(half8*)(&Ks[srow + i * 64][sscol]) = kreg[i];
        for (int i = 0; i < 2; i++)
            *(half8*)(&Vs[vrow + i * 32][vgcol]) = vreg[i];
        __syncthreads();
        if (kt < 15) {
            const int kb = (kt + 1) * 128;
            for (int i = 0; i < 2; i++)
                kreg[i] = *(const half8*)(Kbase + (kb + srow + i * 64) * 64 + sgcol);
            for (int i = 0; i < 2; i++)
                vreg[i] = *(const half8*)(Vbase + (vrow + i * 32) * 2048 + kb + vgcol);
        }

#pragma unroll
        for (int nii = 0; nii < 4; nii++) {
            const int ni = kh * 4 + nii;
            half8 ka = *(const half8*)(&Ks[ni * 16 + l15][(quad ^ akey) * 8]);
            half8 kb2 = *(const half8*)(&Ks[ni * 16 + l15][((quad + 4) ^ akey) * 8]);
            f32x4 s0 = {}, s1 = {};
            s0 = MFMA16(ka, qf[0][0], s0);
            s0 = MFMA16(kb2, qf[0][1], s0);
            s1 = MFMA16(ka, qf[1][0], s1);
            s1 = MFMA16(kb2, qf[1][1], s1);
            half4 bP0, bP1;
            float e;
            e = EXP2F(s0[0]); bP0[0] = (_Float16)e;
            e = EXP2F(s0[1]); bP0[1] = (_Float16)e;
            e = EXP2F(s0[2]); bP0[2] = (_Float16)e;
            e = EXP2F(s0[3]); bP0[3] = (_Float16)e;
            e = EXP2F(s1[0]); bP1[0] = (_Float16)e;
            e = EXP2F(s1[1]); bP1[1] = (_Float16)e;
            e = EXP2F(s1[2]); bP1[2] = (_Float16)e;
            e = EXP2F(s1[3]); bP1[3] = (_Float16)e;
            lacc[0] = MFMA16K16(vone, bP0, lacc[0]);
            lacc[1] = MFMA16K16(vone, bP1, lacc[1]);
#pragma unroll
            for (int di = 0; di < 4; di++) {
                half4 av = *(const half4*)(&Vs[di * 16 + l15][ni * 16 + quad * 4]);
                oacc[0][di] = MFMA16K16(av, bP0, oacc[0][di]);
                oacc[1][di] = MFMA16K16(av, bP1, oacc[1][di]);
            }
        }
    }

    // ---- cross-wave (ni-half) combine: partials are pure sums ----
    float lsum[2] = {lacc[0][0], lacc[1][0]};   // tile-complete per (g,l15)
    float* cb = (float*)&Ks[0][0];   // 4096 floats (exactly Ks)
    float* lb = (float*)&Vs[0][0];   // 512 floats used
    const int pid = pw * 64 + lane;  // 0..255, lane-major -> conflict-free

    __syncthreads();                 // all reads of Ks/Vs done before reuse
    if (kh == 1) {
#pragma unroll
        for (int g = 0; g < 2; g++)
#pragma unroll
            for (int di = 0; di < 2; di++)
#pragma unroll
                for (int j = 0; j < 4; j++)
                    cb[(((g << 1) | di) * 4 + j) * 256 + pid] = oacc[g][di][j];
        lb[pid * 2 + 0] = lsum[0];
        lb[pid * 2 + 1] = lsum[1];
    }
    __syncthreads();
    if (kh == 0) {
#pragma unroll
        for (int g = 0; g < 2; g++)
#pragma unroll
            for (int di = 0; di < 2; di++)
#pragma unroll
                for (int j = 0; j < 4; j++)
                    oacc[g][di][j] += cb[(((g << 1) | di) * 4 + j) * 256 + pid];
        lsum[0] += lb[pid * 2 + 0];
        lsum[1] += lb[pid * 2 + 1];
    }
    __syncthreads();
    if (kh == 1) {
#pragma unroll
        for (int g = 0; g < 2; g++)
#pragma unroll
            for (int di = 2; di < 4; di++)
#pragma unroll
                for (int j = 0; j < 4; j++)
                    cb[(((g << 1) | (di - 2)) * 4 + j) * 256 + pid] = oacc[g][di][j];
    }
    __syncthreads();
    if (kh == 0) {
#pragma unroll
        for (int g = 0; g < 2; g++)
#pragma unroll
            for (int di = 2; di < 4; di++)
#pragma unroll
                for (int j = 0; j < 4; j++)
                    oacc[g][di][j] += cb[(((g << 1) | (di - 2)) * 4 + j) * 256 + pid];

        for (int g = 0; g < 2; g++) {
            float inv = 1.f / lsum[g];
            const int qrow = q0 + pw * 32 + g * 16 + l15;
            for (int di = 0; di < 4; di++) {
                half4 hv;
                hv[0] = (_Float16)(oacc[g][di][0] * inv);
                hv[1] = (_Float16)(oacc[g][di][1] * inv);
                hv[2] = (_Float16)(oacc[g][di][2] * inv);
                hv[3] = (_Float16)(oacc[g][di][3] * inv);
                *(half4*)(&AO[(size_t)(b * 2048 + qrow) * 1024 + h * 64 + di * 16 + quad * 4]) = hv;
            }
        }
    }
}

// ---------------- proj GEMM: out[4096,1024] = AO @ Wp + bp (fp32 out) ----------------

__global__ __launch_bounds__(256) void gemm_proj(const _Float16* __restrict__ A,
                                                 const _Float16* __restrict__ Bt,
                                                 const float* __restrict__ bias,
                                                 float* __restrict__ out) {
    __shared__ _Float16 As[64][64];    //  8 KB
    __shared__ _Float16 Bs[128][64];   // 16 KB
    const int tid = threadIdx.x;
    const int lin = blockIdx.x + 8 * blockIdx.y;
    const int xcd = lin & 7, slot = lin >> 3;     // slot 0..63
    const int n0 = (slot >> 3) * 128;
    const int m0 = (xcd * 8 + (slot & 7)) * 64;
    const int wave = tid >> 6, lane = tid & 63;
    const int quad = lane >> 4, l15 = lane & 15;
    const int sw = l15 & 7;
    const int ldrowA = wave * 16 + (lane >> 3);
    const int ldrowB = wave * 32 + (lane >> 3);
    const int ldslot = (lane & 7) * 8;
    const int gcolA = (((lane & 7) ^ (ldrowA & 7))) * 8;
    const int gcolB = (((lane & 7) ^ (ldrowB & 7))) * 8;

    f32x4 acc[4][2] = {};
    for (int k0 = 0; k0 < 1024; k0 += 64) {
        __syncthreads();
        for (int i = 0; i < 2; i++) {
            int r = ldrowA + i * 8;
            GLOBAL_LOAD_LDS16(&A[(size_t)(m0 + r) * 1024 + k0 + gcolA], &As[r][ldslot]);
        }
        for (int i = 0; i < 4; i++) {
            int r = ldrowB + i * 8;
            GLOBAL_LOAD_LDS16(&Bt[(size_t)(n0 + r) * 1024 + k0 + gcolB], &Bs[r][ldslot]);
        }
        __syncthreads();
        for (int kk = 0; kk < 64; kk += 32) {
            const int rcol = (((kk >> 3) + quad) ^ sw) * 8;
            half8 af[4], bf[2];
            for (int mi = 0; mi < 4; mi++)
                af[mi] = *(const half8*)(&As[mi * 16 + l15][rcol]);
            for (int ni = 0; ni < 2; ni++)
                bf[ni] = *(const half8*)(&Bs[wave * 32 + ni * 16 + l15][rcol]);
            for (int mi = 0; mi < 4; mi++)
                for (int ni = 0; ni < 2; ni++)
                    acc[mi][ni] = MFMA16(af[mi], bf[ni], acc[mi][ni]);
        }
    }
    for (int mi = 0; mi < 4; mi++)
        for (int ni = 0; ni < 2; ni++) {
            int gn = n0 + wave * 32 + ni * 16 + l15;
            float bv = bias[gn];
            for (int r = 0; r < 4; r++) {
                int gm = m0 + mi * 16 + quad * 4 + r;
                out[(size_t)gm * 1024 + gn] = acc[mi][ni][r] + bv;
            }
        }
}

// ---------------- launch ----------------

extern "C" void kernel_launch(void* const* d_in, const int* in_sizes, int n_in,
                              void* d_out, int out_size, void* d_ws, size_t ws_size,
                              hipStream_t stream) {
    const float* x     = (const float*)d_in[0];
    const float* Wqkv  = (const float*)d_in[1];
    const float* bqkv  = (const float*)d_in[2];
    const float* Wproj = (const float*)d_in[3];
    const float* bproj = (const float*)d_in[4];
    float* out = (float*)d_out;

    char* ws = (char*)d_ws;
    const size_t MB = 1024 * 1024;
    _Float16* Xh  = (_Float16*)(ws + 0 * MB);   // [4096][1024]   8 MB
    _Float16* Wqt = (_Float16*)(ws + 8 * MB);   // [3072][1024]   6 MB
    _Float16* Wpt = (_Float16*)(ws + 14 * MB);  // [1024][1024]   2 MB
    _Float16* Qg  = (_Float16*)(ws + 16 * MB);  // [32][2048][64] 8 MB (pre-scaled)
    _Float16* Kg  = (_Float16*)(ws + 24 * MB);  // [32][2048][64] 8 MB
    _Float16* Vtg = (_Float16*)(ws + 32 * MB);  // [32][64][2048] 8 MB
    _Float16* AO  = (_Float16*)(ws + 40 * MB);  // [4096][1024]   8 MB

    prep_kernel<<<8192, 256, 0, stream>>>(x, Wqkv, Wproj, Xh, Wqt, Wpt);
    gemm_qkv<<<192, 512, 0, stream>>>(Xh, Wqt, bqkv, Qg, Kg, Vtg);
    attn_kernel<<<dim3(32, 16), 512, 0, stream>>>(Qg, Kg, Vtg, AO);
    gemm_proj<<<dim3(8, 64), 256, 0, stream>>>(AO, Wpt, bproj, out);
}

// Round 4
// 175.516 us; speedup vs baseline: 1.1338x; 1.0071x over previous
//
#include <hip/hip_runtime.h>

typedef _Float16 half8 __attribute__((ext_vector_type(8)));
typedef _Float16 half4 __attribute__((ext_vector_type(4)));
typedef _Float16 half2 __attribute__((ext_vector_type(2)));
typedef float f32x4 __attribute__((ext_vector_type(4)));
typedef unsigned int u32x4 __attribute__((ext_vector_type(4)));

#define MFMA16(a, b, c) __builtin_amdgcn_mfma_f32_16x16x32_f16((a), (b), (c), 0, 0, 0)
#define EXP2F(x) __builtin_amdgcn_exp2f(x)

#define GLOBAL_LOAD_LDS16(gptr, lptr)                                        \
    __builtin_amdgcn_global_load_lds(                                        \
        (const __attribute__((address_space(1))) void*)(gptr),               \
        (__attribute__((address_space(3))) void*)(lptr), 16, 0, 0)

// Q is pre-scaled by softmax_scale * log2(e) in the qkv epilogue.
#define QSCALE 0.18033688f  // 0.125 * log2(e)

// ---------------- fused prep: cast x + transpose-cast both weights ----------------

__global__ __launch_bounds__(256) void prep_kernel(const float* __restrict__ x,
                                                   const float* __restrict__ Wqkv,
                                                   const float* __restrict__ Wproj,
                                                   _Float16* __restrict__ Xh,
                                                   _Float16* __restrict__ Wqt,
                                                   _Float16* __restrict__ Wpt) {
    const int bid = blockIdx.x;
    const int tid = threadIdx.x;
    if (bid < 4096) {
        int i = bid * 1024 + tid * 4;
        float4 v = *(const float4*)(x + i);
        half4 h = {(_Float16)v.x, (_Float16)v.y, (_Float16)v.z, (_Float16)v.w};
        *(half4*)(Xh + i) = h;
        return;
    }
    __shared__ _Float16 tile[32][33];
    const float* W;
    _Float16* Wt;
    int n0, k0, N;
    if (bid < 7168) {
        int t = bid - 4096;
        W = Wqkv; Wt = Wqt; N = 3072;
        n0 = (t % 96) * 32; k0 = (t / 96) * 32;
    } else {
        int t = bid - 7168;
        W = Wproj; Wt = Wpt; N = 1024;
        n0 = (t & 31) * 32; k0 = (t >> 5) * 32;
    }
    int c = tid & 31, r4 = tid >> 5;
    for (int i = 0; i < 4; i++) {
        int r = r4 + i * 8;
        tile[r][c] = (_Float16)W[(k0 + r) * N + n0 + c];
    }
    __syncthreads();
    for (int i = 0; i < 4; i++) {
        int r = r4 + i * 8;  // n within tile
        Wt[(n0 + r) * 1024 + k0 + c] = tile[c][r];
    }
}

// ---------------- QKV GEMM: 256x256-tile 8-phase counted-vmcnt (T2+T3+T4+T5) ----------------

#define SCHED0() __builtin_amdgcn_sched_barrier(0)
#define BARRIER() do { SCHED0(); asm volatile("" ::: "memory");            \
                       __builtin_amdgcn_s_barrier();                        \
                       asm volatile("" ::: "memory"); SCHED0(); } while (0)
#define WAITV(N) asm volatile("s_waitcnt vmcnt(" #N ")" ::: "memory")

#define LOFF(ROW, Q) ((((ROW) >> 1) * 64) + \
    ((((((ROW) & 1) << 2) | (Q)) ^ (((ROW) >> 1) & 7)) * 8))

__global__ __launch_bounds__(512) void gemm_qkv(const _Float16* __restrict__ A,
                                                const _Float16* __restrict__ Bt,
                                                const float* __restrict__ bias,
                                                _Float16* __restrict__ Qo,
                                                _Float16* __restrict__ Ko,
                                                _Float16* __restrict__ Vto) {
    __shared__ _Float16 L[65536];  // [buf2][op2][kk2][8192 halfs] = 128 KB
    const int tid = threadIdx.x;
    const int lin = blockIdx.x;
    const int xcd = lin & 7, slot = lin >> 3;      // slot 0..23
    const int m0 = (xcd * 2 + slot / 12) * 256;    // 16 m-tiles
    const int n0 = (slot % 12) * 256;              // 12 n-tiles
    const int wave = tid >> 6, lane = tid & 63;
    const int wm = wave >> 2, wn = wave & 3;       // 2M x 4N waves
    const int quad = lane >> 4, l15 = lane & 15;

    // staging: linear GLL dest (lane*16B), pre-swizzled global source
    const int s8 = (tid & 7) ^ ((tid >> 3) & 7);   // logical 16B-slot (0..7)
    const int srow = (tid >> 3) * 2 + (s8 >> 2);   // logical row (round 0)
    const int scol = (s8 & 3) * 8;                 // logical col within kk-half
    const _Float16* Asrc = A + (size_t)(m0 + srow) * 1024 + scol;
    const _Float16* Bsrc = Bt + (size_t)(n0 + srow) * 1024 + scol;
    _Float16* Ldst = L + tid * 8;

#define STG(OP, KK, KT) do {                                                  \
    const _Float16* _g = ((OP) ? Bsrc : Asrc) + ((KT) & 15) * 64 + (KK) * 32; \
    _Float16* _l = Ldst + ((KT) & 1) * 32768 + (OP) * 16384 + (KK) * 8192;    \
    GLOBAL_LOAD_LDS16(_g, _l);                                                \
    GLOBAL_LOAD_LDS16(_g + 128 * 1024, _l + 4096);                            \
} while (0)

    const int arow = wm * 128 + l15;   // + MH*64 + fi*16
    const int brow = wn * 64 + l15;    // + nf*16

    f32x4 acc[8][4] = {};
    half8 af[4], bf[4];

#define PHASE(BUF, KK, MH, RDB, SOP, SKK, SKT, W4) do {                        \
    const _Float16* _ab = L + (BUF) * 32768 + (KK) * 8192;                     \
    const _Float16* _bb = _ab + 16384;                                         \
    if (RDB) {                                                                 \
        _Pragma("unroll") for (int nf = 0; nf < 4; nf++)                       \
            bf[nf] = *(const half8*)(_bb + LOFF(brow + nf * 16, quad));        \
    }                                                                          \
    _Pragma("unroll") for (int fi = 0; fi < 4; fi++)                           \
        af[fi] = *(const half8*)(_ab + LOFF(arow + (MH) * 64 + fi * 16, quad));\
    STG(SOP, SKK, SKT);                                                        \
    BARRIER();                                                                 \
    __builtin_amdgcn_s_setprio(1);                                             \
    _Pragma("unroll") for (int fi = 0; fi < 4; fi++)                           \
        _Pragma("unroll") for (int nf = 0; nf < 4; nf++)                       \
            acc[(MH) * 4 + fi][nf] = MFMA16(af[fi], bf[nf],                    \
                                            acc[(MH) * 4 + fi][nf]);           \
    __builtin_amdgcn_s_setprio(0);                                             \
    if (W4) { WAITV(4); }                                                      \
    BARRIER();                                                                 \
} while (0)

    // prologue: tile0 complete + tile1 lo-halves in flight
    STG(0, 0, 0); STG(1, 0, 0); STG(0, 1, 0); STG(1, 1, 0);
    STG(0, 0, 1); STG(1, 0, 1);
    WAITV(4);           // tile0's 8 loads done; tile1 lo (4 loads) in flight
    BARRIER();

    for (int i = 0; i < 8; ++i) {
        const int ta = 2 * i, tb = 2 * i + 1;
        PHASE(0, 0, 0, 1, 0, 1, tb,     0);  // p1: +stage A-hi(t+1)
        PHASE(0, 0, 1, 0, 1, 1, tb,     0);  // p2: +stage B-hi(t+1)
        PHASE(0, 1, 0, 1, 0, 0, ta + 2, 0);  // p3: +stage A-lo(t+2)
        PHASE(0, 1, 1, 0, 1, 0, ta + 2, 1);  // p4: +stage B-lo(t+2); vmcnt(4)
        PHASE(1, 0, 0, 1, 0, 1, ta + 2, 0);  // p5: +stage A-hi(t+2)
        PHASE(1, 0, 1, 0, 1, 1, ta + 2, 0);  // p6: +stage B-hi(t+2)
        PHASE(1, 1, 0, 1, 0, 0, tb + 2, 0);  // p7: +stage A-lo(t+3)
        PHASE(1, 1, 1, 0, 1, 0, tb + 2, 1);  // p8: +stage B-lo(t+3); vmcnt(4)
    }
    WAITV(0);  // drain trailing (wrapped) stages before epilogue / endpgm

    // epilogue: scatter to Q (scaled) / K / Vt. which is block-uniform.
    const int which = n0 >> 10;
    const int hh = ((n0 + wn * 64) & 1023) >> 6;  // head idx (wave-uniform)
    float bv[4];
    const int gnb = n0 + wn * 64;
#pragma unroll
    for (int nf = 0; nf < 4; nf++) bv[nf] = bias[gnb + nf * 16 + l15];

#pragma unroll
    for (int mf = 0; mf < 8; mf++) {
        const int gm0 = m0 + wm * 128 + mf * 16 + quad * 4;
        const int b = gm0 >> 11, t0 = gm0 & 2047;
        const int bh = b * 16 + hh;
#pragma unroll
        for (int nf = 0; nf < 4; nf++) {
            const int dh = nf * 16 + l15;
            if (which == 2) {
                half4 hv;
#pragma unroll
                for (int r = 0; r < 4; r++)
                    hv[r] = (_Float16)(acc[mf][nf][r] + bv[nf]);
                *(half4*)(&Vto[(size_t)(bh * 64 + dh) * 2048 + t0]) = hv;
            } else if (which == 0) {
#pragma unroll
                for (int r = 0; r < 4; r++)
                    Qo[((size_t)bh * 2048 + t0 + r) * 64 + dh] =
                        (_Float16)((acc[mf][nf][r] + bv[nf]) * QSCALE);
            } else {
#pragma unroll
                for (int r = 0; r < 4; r++)
                    Ko[((size_t)bh * 2048 + t0 + r) * 64 + dh] =
                        (_Float16)(acc[mf][nf][r] + bv[nf]);
            }
        }
    }
#undef PHASE
#undef STG
}

// ---------------- flash attention: 8-wave ni-split, all-K32 MFMA, sigma-V ----------------
// PV uses 16x16x32 (K16 PV cost ~= K32 cost but half the FLOPs, R2 counters).
// NO cross-lane redistribution of P: after QK^T, lane (quad,j) natively holds
// P k-labels {4q+j | j<4} (sA regs) u {16+4q+(j-4) | j>=4} (sB regs). We pack
// bP = {sA[0..3], sB[0..3]} as-is, and store V^T in LDS with the MATCHING
// position map within each 32-k block:
//   sigma(k) = ((k>>2)&3)*8 + ((k>>4)&1)*4 + (k&3)
// so A (V) and B (P) agree on k at every MFMA position. Derived purely from
// the documented A/B/C fragment layouts (same ones all passing kernels use).
// Row-sum via ones-K32 MFMA (permutation-invariant). Matrix cyc/wave/kt -26%.

static __device__ inline unsigned pk2(float a, float b) {
    half2 p;
    p.x = (_Float16)a;
    p.y = (_Float16)b;
    return __builtin_bit_cast(unsigned, p);
}

__global__ __launch_bounds__(512, 4) void attn_kernel(const _Float16* __restrict__ Qg,
                                                      const _Float16* __restrict__ Kg,
                                                      const _Float16* __restrict__ Vtg,
                                                      _Float16* __restrict__ AO) {
    __shared__ __align__(16) _Float16 Ks[128][64];    // 16 KB, XOR-swizzled
    __shared__ __align__(16) _Float16 Vs[64][136];    // 17 KB, sigma-permuted cols

    const int tid = threadIdx.x;
    const int bh = blockIdx.x;
    const int q0 = blockIdx.y * 128;
    const int b = bh >> 4, h = bh & 15;
    const int wave = tid >> 6, lane = tid & 63;
    const int pw = wave & 3;     // q-group (32 q)
    const int kh = wave >> 2;    // ni half: k-cols [kh*64, kh*64+64)
    const int quad = lane >> 4, l15 = lane & 15;
    const int akey = l15 & 7;

    half8 qf[2][2];
    for (int g = 0; g < 2; g++) {
        const int qrow = q0 + pw * 32 + g * 16 + l15;
        for (int kk = 0; kk < 2; kk++)
            qf[g][kk] = *(const half8*)(&Qg[(bh * 2048 + qrow) * 64 + kk * 32 + quad * 8]);
    }

    // staging (512 threads: 2 rounds each for K and V)
    const int srow = tid >> 3;           // 0..63
    const int sc8 = tid & 7;
    const int sgcol = sc8 * 8;
    const int sscol = (sc8 ^ (srow & 7)) * 8;
    const int vrow = tid >> 4;           // 0..31
    const int vgcol = (tid & 15) * 8;    // global col (8-aligned)
    // sigma store split: contiguous global half8 [c0..c0+7] -> two half4 at
    // sigma(c0) and sigma(c0)+8 (since k -> k+4 within a half jumps q by 1).
    const int vb32 = vgcol & 96;
    const int vc32 = vgcol & 31;                                  // {0,8,16,24}
    const int vsiga = ((vc32 & 8) << 1) | ((vc32 & 16) >> 2);     // {0,16,4,20}

    const _Float16* Kbase = Kg + (size_t)bh * 2048 * 64;
    const _Float16* Vbase = Vtg + (size_t)bh * 64 * 2048;

    half8 kreg[2], vreg[2];
    for (int i = 0; i < 2; i++)
        kreg[i] = *(const half8*)(Kbase + (srow + i * 64) * 64 + sgcol);
    for (int i = 0; i < 2; i++)
        vreg[i] = *(const half8*)(Vbase + (vrow + i * 32) * 2048 + vgcol);

    const half8 vone8 = {(_Float16)1.f, (_Float16)1.f, (_Float16)1.f, (_Float16)1.f,
                         (_Float16)1.f, (_Float16)1.f, (_Float16)1.f, (_Float16)1.f};
    f32x4 lacc[2] = {};
    f32x4 oacc[2][4] = {};

    for (int kt = 0; kt < 16; kt++) {
        __syncthreads();
        for (int i = 0; i < 2; i++)
            *(half8*)(&Ks[srow + i * 64][sscol]) = kreg[i];
#pragma unroll
        for (int i = 0; i < 2; i++) {
            half4 lo = __builtin_shufflevector(vreg[i], vreg[i], 0, 1, 2, 3);
            half4 hi = __builtin_shufflevector(vreg[i], vreg[i], 4, 5, 6, 7);
            *(half4*)(&Vs[vrow + i * 32][vb32 + vsiga]) = lo;
            *(half4*)(&Vs[vrow + i * 32][vb32 + vsiga + 8]) = hi;
        }
        __syncthreads();
        if (kt < 15) {
            const int kb = (kt + 1) * 128;
            for (int i = 0; i < 2; i++)
                kreg[i] = *(const half8*)(Kbase + (kb + srow + i * 64) * 64 + sgcol);
            for (int i = 0; i < 2; i++)
                vreg[i] = *(const half8*)(Vbase + (vrow + i * 32) * 2048 + kb + vgcol);
        }

#pragma unroll
        for (int ni2 = 0; ni2 < 2; ni2++) {
            const int nia = kh * 4 + ni2 * 2;   // 16-block a: k rows [nia*16,+16)
            half8 kaa = *(const half8*)(&Ks[nia * 16 + l15][(quad ^ akey) * 8]);
            half8 kab = *(const half8*)(&Ks[nia * 16 + l15][((quad + 4) ^ akey) * 8]);
            half8 kba = *(const half8*)(&Ks[(nia + 1) * 16 + l15][(quad ^ akey) * 8]);
            half8 kbb = *(const half8*)(&Ks[(nia + 1) * 16 + l15][((quad + 4) ^ akey) * 8]);
            f32x4 sA0 = {}, sB0 = {}, sA1 = {}, sB1 = {};
            sA0 = MFMA16(kaa, qf[0][0], sA0);
            sA0 = MFMA16(kab, qf[0][1], sA0);
            sB0 = MFMA16(kba, qf[0][0], sB0);
            sB0 = MFMA16(kbb, qf[0][1], sB0);
            sA1 = MFMA16(kaa, qf[1][0], sA1);
            sA1 = MFMA16(kab, qf[1][1], sA1);
            sB1 = MFMA16(kba, qf[1][0], sB1);
            sB1 = MFMA16(kbb, qf[1][1], sB1);

            // exp2 -> f16 pack in NATIVE order: lane (quad) holds k-labels
            // {4q..4q+3} (j<4, from sA) and {16+4q..16+4q+3} (j>=4, from sB).
            u32x4 w0 = {pk2(EXP2F(sA0[0]), EXP2F(sA0[1])),
                        pk2(EXP2F(sA0[2]), EXP2F(sA0[3])),
                        pk2(EXP2F(sB0[0]), EXP2F(sB0[1])),
                        pk2(EXP2F(sB0[2]), EXP2F(sB0[3]))};
            half8 bP0 = __builtin_bit_cast(half8, w0);
            u32x4 w1 = {pk2(EXP2F(sA1[0]), EXP2F(sA1[1])),
                        pk2(EXP2F(sA1[2]), EXP2F(sA1[3])),
                        pk2(EXP2F(sB1[0]), EXP2F(sB1[1])),
                        pk2(EXP2F(sB1[2]), EXP2F(sB1[3]))};
            half8 bP1 = __builtin_bit_cast(half8, w1);

            lacc[0] = MFMA16(vone8, bP0, lacc[0]);
            lacc[1] = MFMA16(vone8, bP1, lacc[1]);

            const int vcb = kh * 64 + ni2 * 32 + quad * 8;
#pragma unroll
            for (int di = 0; di < 4; di++) {
                half8 av = *(const half8*)(&Vs[di * 16 + l15][vcb]);
                oacc[0][di] = MFMA16(av, bP0, oacc[0][di]);
                oacc[1][di] = MFMA16(av, bP1, oacc[1][di]);
            }
        }
    }

    // ---- cross-wave (ni-half) combine: partials are pure sums ----
    float lsum[2] = {lacc[0][0], lacc[1][0]};   // all C-rows equal (ones-A)
    float* cb = (float*)&Ks[0][0];   // 4096 floats (exactly Ks)
    float* lb = (float*)&Vs[0][0];   // 512 floats used
    const int pid = pw * 64 + lane;  // 0..255, lane-major -> conflict-free

    __syncthreads();                 // all reads of Ks/Vs done before reuse
    if (kh == 1) {
#pragma unroll
        for (int g = 0; g < 2; g++)
#pragma unroll
            for (int di = 0; di < 2; di++)
#pragma unroll
                for (int j = 0; j < 4; j++)
                    cb[(((g << 1) | di) * 4 + j) * 256 + pid] = oacc[g][di][j];
        lb[pid * 2 + 0] = lsum[0];
        lb[pid * 2 + 1] = lsum[1];
    }
    __syncthreads();
    if (kh == 0) {
#pragma unroll
        for (int g = 0; g < 2; g++)
#pragma unroll
            for (int di = 0; di < 2; di++)
#pragma unroll
                for (int j = 0; j < 4; j++)
                    oacc[g][di][j] += cb[(((g << 1) | di) * 4 + j) * 256 + pid];
        lsum[0] += lb[pid * 2 + 0];
        lsum[1] += lb[pid * 2 + 1];
    }
    __syncthreads();
    if (kh == 1) {
#pragma unroll
        for (int g = 0; g < 2; g++)
#pragma unroll
            for (int di = 2; di < 4; di++)
#pragma unroll
                for (int j = 0; j < 4; j++)
                    cb[(((g << 1) | (di - 2)) * 4 + j) * 256 + pid] = oacc[g][di][j];
    }
    __syncthreads();
    if (kh == 0) {
#pragma unroll
        for (int g = 0; g < 2; g++)
#pragma unroll
            for (int di = 2; di < 4; di++)
#pragma unroll
                for (int j = 0; j < 4; j++)
                    oacc[g][di][j] += cb[(((g << 1) | (di - 2)) * 4 + j) * 256 + pid];

        for (int g = 0; g < 2; g++) {
            float inv = 1.f / lsum[g];
            const int qrow = q0 + pw * 32 + g * 16 + l15;
            for (int di = 0; di < 4; di++) {
                half4 hv;
                hv[0] = (_Float16)(oacc[g][di][0] * inv);
                hv[1] = (_Float16)(oacc[g][di][1] * inv);
                hv[2] = (_Float16)(oacc[g][di][2] * inv);
                hv[3] = (_Float16)(oacc[g][di][3] * inv);
                *(half4*)(&AO[(size_t)(b * 2048 + qrow) * 1024 + h * 64 + di * 16 + quad * 4]) = hv;
            }
        }
    }
}

// ---------------- proj GEMM: out[4096,1024] = AO @ Wp + bp (fp32 out) ----------------

__global__ __launch_bounds__(256) void gemm_proj(const _Float16* __restrict__ A,
                                                 const _Float16* __restrict__ Bt,
                                                 const float* __restrict__ bias,
                                                 float* __restrict__ out) {
    __shared__ _Float16 As[64][64];    //  8 KB
    __shared__ _Float16 Bs[128][64];   // 16 KB
    const int tid = threadIdx.x;
    const int lin = blockIdx.x + 8 * blockIdx.y;
    const int xcd = lin & 7, slot = lin >> 3;     // slot 0..63
    const int n0 = (slot >> 3) * 128;
    const int m0 = (xcd * 8 + (slot & 7)) * 64;
    const int wave = tid >> 6, lane = tid & 63;
    const int quad = lane >> 4, l15 = lane & 15;
    const int sw = l15 & 7;
    const int ldrowA = wave * 16 + (lane >> 3);
    const int ldrowB = wave * 32 + (lane >> 3);
    const int ldslot = (lane & 7) * 8;
    const int gcolA = (((lane & 7) ^ (ldrowA & 7))) * 8;
    const int gcolB = (((lane & 7) ^ (ldrowB & 7))) * 8;

    f32x4 acc[4][2] = {};
    for (int k0 = 0; k0 < 1024; k0 += 64) {
        __syncthreads();
        for (int i = 0; i < 2; i++) {
            int r = ldrowA + i * 8;
            GLOBAL_LOAD_LDS16(&A[(size_t)(m0 + r) * 1024 + k0 + gcolA], &As[r][ldslot]);
        }
        for (int i = 0; i < 4; i++) {
            int r = ldrowB + i * 8;
            GLOBAL_LOAD_LDS16(&Bt[(size_t)(n0 + r) * 1024 + k0 + gcolB], &Bs[r][ldslot]);
        }
        __syncthreads();
        for (int kk = 0; kk < 64; kk += 32) {
            const int rcol = (((kk >> 3) + quad) ^ sw) * 8;
            half8 af[4], bf[2];
            for (int mi = 0; mi < 4; mi++)
                af[mi] = *(const half8*)(&As[mi * 16 + l15][rcol]);
            for (int ni = 0; ni < 2; ni++)
                bf[ni] = *(const half8*)(&Bs[wave * 32 + ni * 16 + l15][rcol]);
            for (int mi = 0; mi < 4; mi++)
                for (int ni = 0; ni < 2; ni++)
                    acc[mi][ni] = MFMA16(af[mi], bf[ni], acc[mi][ni]);
        }
    }
    for (int mi = 0; mi < 4; mi++)
        for (int ni = 0; ni < 2; ni++) {
            int gn = n0 + wave * 32 + ni * 16 + l15;
            float bv = bias[gn];
            for (int r = 0; r < 4; r++) {
                int gm = m0 + mi * 16 + quad * 4 + r;
                out[(size_t)gm * 1024 + gn] = acc[mi][ni][r] + bv;
            }
        }
}

// ---------------- launch ----------------

extern "C" void kernel_launch(void* const* d_in, const int* in_sizes, int n_in,
                              void* d_out, int out_size, void* d_ws, size_t ws_size,
                              hipStream_t stream) {
    const float* x     = (const float*)d_in[0];
    const float* Wqkv  = (const float*)d_in[1];
    const float* bqkv  = (const float*)d_in[2];
    const float* Wproj = (const float*)d_in[3];
    const float* bproj = (const float*)d_in[4];
    float* out = (float*)d_out;

    char* ws = (char*)d_ws;
    const size_t MB = 1024 * 1024;
    _Float16* Xh  = (_Float16*)(ws + 0 * MB);   // [4096][1024]   8 MB
    _Float16* Wqt = (_Float16*)(ws + 8 * MB);   // [3072][1024]   6 MB
    _Float16* Wpt = (_Float16*)(ws + 14 * MB);  // [1024][1024]   2 MB
    _Float16* Qg  = (_Float16*)(ws + 16 * MB);  // [32][2048][64] 8 MB (pre-scaled)
    _Float16* Kg  = (_Float16*)(ws + 24 * MB);  // [32][2048][64] 8 MB
    _Float16* Vtg = (_Float16*)(ws + 32 * MB);  // [32][64][2048] 8 MB
    _Float16* AO  = (_Float16*)(ws + 40 * MB);  // [4096][1024]   8 MB

    prep_kernel<<<8192, 256, 0, stream>>>(x, Wqkv, Wproj, Xh, Wqt, Wpt);
    gemm_qkv<<<192, 512, 0, stream>>>(Xh, Wqt, bqkv, Qg, Kg, Vtg);
    attn_kernel<<<dim3(32, 16), 512, 0, stream>>>(Qg, Kg, Vtg, AO);
    gemm_proj<<<dim3(8, 64), 256, 0, stream>>>(AO, Wpt, bproj, out);
}

// Round 5
// 173.691 us; speedup vs baseline: 1.1457x; 1.0105x over previous
//
#include <hip/hip_runtime.h>

typedef _Float16 half8 __attribute__((ext_vector_type(8)));
typedef _Float16 half4 __attribute__((ext_vector_type(4)));
typedef _Float16 half2 __attribute__((ext_vector_type(2)));
typedef float f32x4 __attribute__((ext_vector_type(4)));
typedef unsigned int u32x4 __attribute__((ext_vector_type(4)));

#define MFMA16(a, b, c) __builtin_amdgcn_mfma_f32_16x16x32_f16((a), (b), (c), 0, 0, 0)
#define EXP2F(x) __builtin_amdgcn_exp2f(x)

#define GLOBAL_LOAD_LDS16(gptr, lptr)                                        \
    __builtin_amdgcn_global_load_lds(                                        \
        (const __attribute__((address_space(1))) void*)(gptr),               \
        (__attribute__((address_space(3))) void*)(lptr), 16, 0, 0)

// Q is pre-scaled by softmax_scale * log2(e) in the qkv epilogue.
#define QSCALE 0.18033688f  // 0.125 * log2(e)

#define SCHED0() __builtin_amdgcn_sched_barrier(0)
#define BARRIER() do { SCHED0(); asm volatile("" ::: "memory");            \
                       __builtin_amdgcn_s_barrier();                        \
                       asm volatile("" ::: "memory"); SCHED0(); } while (0)
#define WAITV(N) asm volatile("s_waitcnt vmcnt(" #N ")" ::: "memory")
#define WAITLG(N) asm volatile("s_waitcnt lgkmcnt(" #N ")" ::: "memory")

// ---------------- fused prep: cast x + transpose-cast both weights ----------------

__global__ __launch_bounds__(256) void prep_kernel(const float* __restrict__ x,
                                                   const float* __restrict__ Wqkv,
                                                   const float* __restrict__ Wproj,
                                                   _Float16* __restrict__ Xh,
                                                   _Float16* __restrict__ Wqt,
                                                   _Float16* __restrict__ Wpt) {
    const int bid = blockIdx.x;
    const int tid = threadIdx.x;
    if (bid < 4096) {
        int i = bid * 1024 + tid * 4;
        float4 v = *(const float4*)(x + i);
        half4 h = {(_Float16)v.x, (_Float16)v.y, (_Float16)v.z, (_Float16)v.w};
        *(half4*)(Xh + i) = h;
        return;
    }
    __shared__ _Float16 tile[32][33];
    const float* W;
    _Float16* Wt;
    int n0, k0, N;
    if (bid < 7168) {
        int t = bid - 4096;
        W = Wqkv; Wt = Wqt; N = 3072;
        n0 = (t % 96) * 32; k0 = (t / 96) * 32;
    } else {
        int t = bid - 7168;
        W = Wproj; Wt = Wpt; N = 1024;
        n0 = (t & 31) * 32; k0 = (t >> 5) * 32;
    }
    int c = tid & 31, r4 = tid >> 5;
    for (int i = 0; i < 4; i++) {
        int r = r4 + i * 8;
        tile[r][c] = (_Float16)W[(k0 + r) * N + n0 + c];
    }
    __syncthreads();
    for (int i = 0; i < 4; i++) {
        int r = r4 + i * 8;  // n within tile
        Wt[(n0 + r) * 1024 + k0 + c] = tile[c][r];
    }
}

// ---------------- QKV GEMM: 256x256-tile 8-phase counted-vmcnt (T2+T3+T4+T5) ----------------

#define LOFF(ROW, Q) ((((ROW) >> 1) * 64) + \
    ((((((ROW) & 1) << 2) | (Q)) ^ (((ROW) >> 1) & 7)) * 8))

__global__ __launch_bounds__(512) void gemm_qkv(const _Float16* __restrict__ A,
                                                const _Float16* __restrict__ Bt,
                                                const float* __restrict__ bias,
                                                _Float16* __restrict__ Qo,
                                                _Float16* __restrict__ Ko,
                                                _Float16* __restrict__ Vto) {
    __shared__ _Float16 L[65536];  // [buf2][op2][kk2][8192 halfs] = 128 KB
    const int tid = threadIdx.x;
    const int lin = blockIdx.x;
    const int xcd = lin & 7, slot = lin >> 3;      // slot 0..23
    const int m0 = (xcd * 2 + slot / 12) * 256;    // 16 m-tiles
    const int n0 = (slot % 12) * 256;              // 12 n-tiles
    const int wave = tid >> 6, lane = tid & 63;
    const int wm = wave >> 2, wn = wave & 3;       // 2M x 4N waves
    const int quad = lane >> 4, l15 = lane & 15;

    // staging: linear GLL dest (lane*16B), pre-swizzled global source
    const int s8 = (tid & 7) ^ ((tid >> 3) & 7);   // logical 16B-slot (0..7)
    const int srow = (tid >> 3) * 2 + (s8 >> 2);   // logical row (round 0)
    const int scol = (s8 & 3) * 8;                 // logical col within kk-half
    const _Float16* Asrc = A + (size_t)(m0 + srow) * 1024 + scol;
    const _Float16* Bsrc = Bt + (size_t)(n0 + srow) * 1024 + scol;
    _Float16* Ldst = L + tid * 8;

#define STG(OP, KK, KT) do {                                                  \
    const _Float16* _g = ((OP) ? Bsrc : Asrc) + ((KT) & 15) * 64 + (KK) * 32; \
    _Float16* _l = Ldst + ((KT) & 1) * 32768 + (OP) * 16384 + (KK) * 8192;    \
    GLOBAL_LOAD_LDS16(_g, _l);                                                \
    GLOBAL_LOAD_LDS16(_g + 128 * 1024, _l + 4096);                            \
} while (0)

    const int arow = wm * 128 + l15;   // + MH*64 + fi*16
    const int brow = wn * 64 + l15;    // + nf*16

    f32x4 acc[8][4] = {};
    half8 af[4], bf[4];

#define PHASE(BUF, KK, MH, RDB, SOP, SKK, SKT, W4) do {                        \
    const _Float16* _ab = L + (BUF) * 32768 + (KK) * 8192;                     \
    const _Float16* _bb = _ab + 16384;                                         \
    if (RDB) {                                                                 \
        _Pragma("unroll") for (int nf = 0; nf < 4; nf++)                       \
            bf[nf] = *(const half8*)(_bb + LOFF(brow + nf * 16, quad));        \
    }                                                                          \
    _Pragma("unroll") for (int fi = 0; fi < 4; fi++)                           \
        af[fi] = *(const half8*)(_ab + LOFF(arow + (MH) * 64 + fi * 16, quad));\
    STG(SOP, SKK, SKT);                                                        \
    BARRIER();                                                                 \
    __builtin_amdgcn_s_setprio(1);                                             \
    _Pragma("unroll") for (int fi = 0; fi < 4; fi++)                           \
        _Pragma("unroll") for (int nf = 0; nf < 4; nf++)                       \
            acc[(MH) * 4 + fi][nf] = MFMA16(af[fi], bf[nf],                    \
                                            acc[(MH) * 4 + fi][nf]);           \
    __builtin_amdgcn_s_setprio(0);                                             \
    if (W4) { WAITV(4); }                                                      \
    BARRIER();                                                                 \
} while (0)

    // prologue: tile0 complete + tile1 lo-halves in flight
    STG(0, 0, 0); STG(1, 0, 0); STG(0, 1, 0); STG(1, 1, 0);
    STG(0, 0, 1); STG(1, 0, 1);
    WAITV(4);           // tile0's 8 loads done; tile1 lo (4 loads) in flight
    BARRIER();

    for (int i = 0; i < 8; ++i) {
        const int ta = 2 * i, tb = 2 * i + 1;
        PHASE(0, 0, 0, 1, 0, 1, tb,     0);  // p1: +stage A-hi(t+1)
        PHASE(0, 0, 1, 0, 1, 1, tb,     0);  // p2: +stage B-hi(t+1)
        PHASE(0, 1, 0, 1, 0, 0, ta + 2, 0);  // p3: +stage A-lo(t+2)
        PHASE(0, 1, 1, 0, 1, 0, ta + 2, 1);  // p4: +stage B-lo(t+2); vmcnt(4)
        PHASE(1, 0, 0, 1, 0, 1, ta + 2, 0);  // p5: +stage A-hi(t+2)
        PHASE(1, 0, 1, 0, 1, 1, ta + 2, 0);  // p6: +stage B-hi(t+2)
        PHASE(1, 1, 0, 1, 0, 0, tb + 2, 0);  // p7: +stage A-lo(t+3)
        PHASE(1, 1, 1, 0, 1, 0, tb + 2, 1);  // p8: +stage B-lo(t+3); vmcnt(4)
    }
    WAITV(0);  // drain trailing (wrapped) stages before epilogue / endpgm

    // epilogue: scatter to Q (scaled) / K / Vt. which is block-uniform.
    // V columns are stored SIGMA-PERMUTED within each 32-t block:
    //   t = 16h + 4q + r  ->  p = (t & ~31) | (q<<3) | (h<<2) | r
    // so attn's PV B-operand (native P pack) and V agree on k with a plain
    // contiguous LDS copy (no swizzled LDS stores -> no bank conflicts).
    const int which = n0 >> 10;
    const int hh = ((n0 + wn * 64) & 1023) >> 6;  // head idx (wave-uniform)
    float bv[4];
    const int gnb = n0 + wn * 64;
#pragma unroll
    for (int nf = 0; nf < 4; nf++) bv[nf] = bias[gnb + nf * 16 + l15];

#pragma unroll
    for (int mf = 0; mf < 8; mf++) {
        const int gm0 = m0 + wm * 128 + mf * 16 + quad * 4;
        const int b = gm0 >> 11, t0 = gm0 & 2047;
        const int bh = b * 16 + hh;
#pragma unroll
        for (int nf = 0; nf < 4; nf++) {
            const int dh = nf * 16 + l15;
            if (which == 2) {
                half4 hv;
#pragma unroll
                for (int r = 0; r < 4; r++)
                    hv[r] = (_Float16)(acc[mf][nf][r] + bv[nf]);
                const int p0 = (t0 & ~31) | (((t0 >> 2) & 3) << 3) | (((t0 >> 4) & 1) << 2);
                *(half4*)(&Vto[(size_t)(bh * 64 + dh) * 2048 + p0]) = hv;
            } else if (which == 0) {
#pragma unroll
                for (int r = 0; r < 4; r++)
                    Qo[((size_t)bh * 2048 + t0 + r) * 64 + dh] =
                        (_Float16)((acc[mf][nf][r] + bv[nf]) * QSCALE);
            } else {
#pragma unroll
                for (int r = 0; r < 4; r++)
                    Ko[((size_t)bh * 2048 + t0 + r) * 64 + dh] =
                        (_Float16)(acc[mf][nf][r] + bv[nf]);
            }
        }
    }
#undef PHASE
#undef STG
}

// ---------------- flash attention: 8-wave ni-split, all-K32, double-buffered ----------------
// R5: (1) sigma moved into global Vtg layout (gemm_qkv epilogue) -> V LDS copy
// is plain contiguous half8, conflict-free; data in LDS bit-identical to R4.
// (2) Ks/Vs double-buffered (66 KB, still 2 blocks/CU): ONE barrier per K-tile.
// K staged via global_load_lds w/ pre-swizzled source (linear dest); V staged
// via regs (stride-136 rows aren't GLL-linear). Next-tile loads issue BEFORE
// compute, land after (vmcnt(0) + V-write + lgkmcnt(0) + barrier).

static __device__ inline unsigned pk2(float a, float b) {
    half2 p;
    p.x = (_Float16)a;
    p.y = (_Float16)b;
    return __builtin_bit_cast(unsigned, p);
}

__global__ __launch_bounds__(512, 4) void attn_kernel(const _Float16* __restrict__ Qg,
                                                      const _Float16* __restrict__ Kg,
                                                      const _Float16* __restrict__ Vtg,
                                                      _Float16* __restrict__ AO) {
    __shared__ __align__(16) _Float16 Ks[2][128][64];    // 32 KB, XOR-swizzled
    __shared__ __align__(16) _Float16 Vs[2][64][136];    // 34 KB, sigma in global

    const int tid = threadIdx.x;
    const int bh = blockIdx.x;
    const int q0 = blockIdx.y * 128;
    const int b = bh >> 4, h = bh & 15;
    const int wave = tid >> 6, lane = tid & 63;
    const int pw = wave & 3;     // q-group (32 q)
    const int kh = wave >> 2;    // ni half: k-cols [kh*64, kh*64+64)
    const int quad = lane >> 4, l15 = lane & 15;
    const int akey = l15 & 7;

    half8 qf[2][2];
    for (int g = 0; g < 2; g++) {
        const int qrow = q0 + pw * 32 + g * 16 + l15;
        for (int kk = 0; kk < 2; kk++)
            qf[g][kk] = *(const half8*)(&Qg[(bh * 2048 + qrow) * 64 + kk * 32 + quad * 8]);
    }

    // K staging: GLL linear dest (tid*16B); pre-swizzled global source so LDS
    // content matches the read-side XOR swizzle (identical to prior reg path).
    const int krow = tid >> 3;                       // rows 0..63 (+64 for i=1)
    const int kgc = ((tid & 7) ^ (krow & 7)) * 8;    // pre-swizzled global col
    const _Float16* Kbase = Kg + (size_t)bh * 2048 * 64;
    const _Float16* Vbase = Vtg + (size_t)bh * 64 * 2048;
    const _Float16* Ksrc = Kbase + (size_t)krow * 64 + kgc;
    _Float16* Kdst = &Ks[0][0][0] + tid * 8;         // + buf*8192, + i*4096

    // V staging: plain contiguous copy (global already sigma-permuted)
    const int vrow = tid >> 4;           // 0..31 (+32 for i=1)
    const int vgcol = (tid & 15) * 8;
    const _Float16* Vsrc = Vbase + (size_t)vrow * 2048 + vgcol;

    const half8 vone8 = {(_Float16)1.f, (_Float16)1.f, (_Float16)1.f, (_Float16)1.f,
                         (_Float16)1.f, (_Float16)1.f, (_Float16)1.f, (_Float16)1.f};
    f32x4 lacc[2] = {};
    f32x4 oacc[2][4] = {};
    half8 vreg[2];

    // prologue: stage tile 0 into buf 0
    GLOBAL_LOAD_LDS16(Ksrc, Kdst);
    GLOBAL_LOAD_LDS16(Ksrc + 4096, Kdst + 4096);
    vreg[0] = *(const half8*)(Vsrc);
    vreg[1] = *(const half8*)(Vsrc + 32 * 2048);
    WAITV(0);
    *(half8*)(&Vs[0][vrow][vgcol]) = vreg[0];
    *(half8*)(&Vs[0][vrow + 32][vgcol]) = vreg[1];
    WAITLG(0);
    BARRIER();

    for (int kt = 0; kt < 16; kt++) {
        const int cur = kt & 1;
        const _Float16 (*Kc)[64] = Ks[cur];
        const _Float16 (*Vc)[136] = Vs[cur];
        if (kt < 15) {
            const size_t ko = (size_t)(kt + 1) * 8192;   // 128 rows * 64
            _Float16* kd = &Ks[cur ^ 1][0][0] + tid * 8;
            GLOBAL_LOAD_LDS16(Ksrc + ko, kd);
            GLOBAL_LOAD_LDS16(Ksrc + ko + 4096, kd + 4096);
            const int kb = (kt + 1) * 128;
            vreg[0] = *(const half8*)(Vsrc + kb);
            vreg[1] = *(const half8*)(Vsrc + 32 * 2048 + kb);
        }

#pragma unroll
        for (int ni2 = 0; ni2 < 2; ni2++) {
            const int nia = kh * 4 + ni2 * 2;   // 16-block a: k rows [nia*16,+16)
            half8 kaa = *(const half8*)(&Kc[nia * 16 + l15][(quad ^ akey) * 8]);
            half8 kab = *(const half8*)(&Kc[nia * 16 + l15][((quad + 4) ^ akey) * 8]);
            half8 kba = *(const half8*)(&Kc[(nia + 1) * 16 + l15][(quad ^ akey) * 8]);
            half8 kbb = *(const half8*)(&Kc[(nia + 1) * 16 + l15][((quad + 4) ^ akey) * 8]);
            f32x4 sA0 = {}, sB0 = {}, sA1 = {}, sB1 = {};
            sA0 = MFMA16(kaa, qf[0][0], sA0);
            sA0 = MFMA16(kab, qf[0][1], sA0);
            sB0 = MFMA16(kba, qf[0][0], sB0);
            sB0 = MFMA16(kbb, qf[0][1], sB0);
            sA1 = MFMA16(kaa, qf[1][0], sA1);
            sA1 = MFMA16(kab, qf[1][1], sA1);
            sB1 = MFMA16(kba, qf[1][0], sB1);
            sB1 = MFMA16(kbb, qf[1][1], sB1);

            // exp2 -> f16 pack in NATIVE order: lane (quad) holds k-labels
            // {4q..4q+3} (j<4, from sA) and {16+4q..16+4q+3} (j>=4, from sB).
            u32x4 w0 = {pk2(EXP2F(sA0[0]), EXP2F(sA0[1])),
                        pk2(EXP2F(sA0[2]), EXP2F(sA0[3])),
                        pk2(EXP2F(sB0[0]), EXP2F(sB0[1])),
                        pk2(EXP2F(sB0[2]), EXP2F(sB0[3]))};
            half8 bP0 = __builtin_bit_cast(half8, w0);
            u32x4 w1 = {pk2(EXP2F(sA1[0]), EXP2F(sA1[1])),
                        pk2(EXP2F(sA1[2]), EXP2F(sA1[3])),
                        pk2(EXP2F(sB1[0]), EXP2F(sB1[1])),
                        pk2(EXP2F(sB1[2]), EXP2F(sB1[3]))};
            half8 bP1 = __builtin_bit_cast(half8, w1);

            lacc[0] = MFMA16(vone8, bP0, lacc[0]);
            lacc[1] = MFMA16(vone8, bP1, lacc[1]);

            const int vcb = kh * 64 + ni2 * 32 + quad * 8;
#pragma unroll
            for (int di = 0; di < 4; di++) {
                half8 av = *(const half8*)(&Vc[di * 16 + l15][vcb]);
                oacc[0][di] = MFMA16(av, bP0, oacc[0][di]);
                oacc[1][di] = MFMA16(av, bP1, oacc[1][di]);
            }
        }

        if (kt < 15) {
            WAITV(0);
            *(half8*)(&Vs[cur ^ 1][vrow][vgcol]) = vreg[0];
            *(half8*)(&Vs[cur ^ 1][vrow + 32][vgcol]) = vreg[1];
            WAITLG(0);
        }
        BARRIER();
    }

    // ---- cross-wave (ni-half) combine: partials are pure sums ----
    float lsum[2] = {lacc[0][0], lacc[1][0]};   // all C-rows equal (ones-A)
    float* cb = (float*)&Ks[0][0][0];   // 4096 floats used
    float* lb = (float*)&Vs[0][0][0];   // 512 floats used
    const int pid = pw * 64 + lane;  // 0..255, lane-major -> conflict-free

    __syncthreads();                 // all reads of Ks/Vs done before reuse
    if (kh == 1) {
#pragma unroll
        for (int g = 0; g < 2; g++)
#pragma unroll
            for (int di = 0; di < 2; di++)
#pragma unroll
                for (int j = 0; j < 4; j++)
                    cb[(((g << 1) | di) * 4 + j) * 256 + pid] = oacc[g][di][j];
        lb[pid * 2 + 0] = lsum[0];
        lb[pid * 2 + 1] = lsum[1];
    }
    __syncthreads();
    if (kh == 0) {
#pragma unroll
        for (int g = 0; g < 2; g++)
#pragma unroll
            for (int di = 0; di < 2; di++)
#pragma unroll
                for (int j = 0; j < 4; j++)
                    oacc[g][di][j] += cb[(((g << 1) | di) * 4 + j) * 256 + pid];
        lsum[0] += lb[pid * 2 + 0];
        lsum[1] += lb[pid * 2 + 1];
    }
    __syncthreads();
    if (kh == 1) {
#pragma unroll
        for (int g = 0; g < 2; g++)
#pragma unroll
            for (int di = 2; di < 4; di++)
#pragma unroll
                for (int j = 0; j < 4; j++)
                    cb[(((g << 1) | (di - 2)) * 4 + j) * 256 + pid] = oacc[g][di][j];
    }
    __syncthreads();
    if (kh == 0) {
#pragma unroll
        for (int g = 0; g < 2; g++)
#pragma unroll
            for (int di = 2; di < 4; di++)
#pragma unroll
                for (int j = 0; j < 4; j++)
                    oacc[g][di][j] += cb[(((g << 1) | (di - 2)) * 4 + j) * 256 + pid];

        for (int g = 0; g < 2; g++) {
            float inv = 1.f / lsum[g];
            const int qrow = q0 + pw * 32 + g * 16 + l15;
            for (int di = 0; di < 4; di++) {
                half4 hv;
                hv[0] = (_Float16)(oacc[g][di][0] * inv);
                hv[1] = (_Float16)(oacc[g][di][1] * inv);
                hv[2] = (_Float16)(oacc[g][di][2] * inv);
                hv[3] = (_Float16)(oacc[g][di][3] * inv);
                *(half4*)(&AO[(size_t)(b * 2048 + qrow) * 1024 + h * 64 + di * 16 + quad * 4]) = hv;
            }
        }
    }
}

// ---------------- proj GEMM: out[4096,1024] = AO @ Wp + bp (fp32 out) ----------------

__global__ __launch_bounds__(256) void gemm_proj(const _Float16* __restrict__ A,
                                                 const _Float16* __restrict__ Bt,
                                                 const float* __restrict__ bias,
                                                 float* __restrict__ out) {
    __shared__ _Float16 As[64][64];    //  8 KB
    __shared__ _Float16 Bs[128][64];   // 16 KB
    const int tid = threadIdx.x;
    const int lin = blockIdx.x + 8 * blockIdx.y;
    const int xcd = lin & 7, slot = lin >> 3;     // slot 0..63
    const int n0 = (slot >> 3) * 128;
    const int m0 = (xcd * 8 + (slot & 7)) * 64;
    const int wave = tid >> 6, lane = tid & 63;
    const int quad = lane >> 4, l15 = lane & 15;
    const int sw = l15 & 7;
    const int ldrowA = wave * 16 + (lane >> 3);
    const int ldrowB = wave * 32 + (lane >> 3);
    const int ldslot = (lane & 7) * 8;
    const int gcolA = (((lane & 7) ^ (ldrowA & 7))) * 8;
    const int gcolB = (((lane & 7) ^ (ldrowB & 7))) * 8;

    f32x4 acc[4][2] = {};
    for (int k0 = 0; k0 < 1024; k0 += 64) {
        __syncthreads();
        for (int i = 0; i < 2; i++) {
            int r = ldrowA + i * 8;
            GLOBAL_LOAD_LDS16(&A[(size_t)(m0 + r) * 1024 + k0 + gcolA], &As[r][ldslot]);
        }
        for (int i = 0; i < 4; i++) {
            int r = ldrowB + i * 8;
            GLOBAL_LOAD_LDS16(&Bt[(size_t)(n0 + r) * 1024 + k0 + gcolB], &Bs[r][ldslot]);
        }
        __syncthreads();
        for (int kk = 0; kk < 64; kk += 32) {
            const int rcol = (((kk >> 3) + quad) ^ sw) * 8;
            half8 af[4], bf[2];
            for (int mi = 0; mi < 4; mi++)
                af[mi] = *(const half8*)(&As[mi * 16 + l15][rcol]);
            for (int ni = 0; ni < 2; ni++)
                bf[ni] = *(const half8*)(&Bs[wave * 32 + ni * 16 + l15][rcol]);
            for (int mi = 0; mi < 4; mi++)
                for (int ni = 0; ni < 2; ni++)
                    acc[mi][ni] = MFMA16(af[mi], bf[ni], acc[mi][ni]);
        }
    }
    for (int mi = 0; mi < 4; mi++)
        for (int ni = 0; ni < 2; ni++) {
            int gn = n0 + wave * 32 + ni * 16 + l15;
            float bv = bias[gn];
            for (int r = 0; r < 4; r++) {
                int gm = m0 + mi * 16 + quad * 4 + r;
                out[(size_t)gm * 1024 + gn] = acc[mi][ni][r] + bv;
            }
        }
}

// ---------------- launch ----------------

extern "C" void kernel_launch(void* const* d_in, const int* in_sizes, int n_in,
                              void* d_out, int out_size, void* d_ws, size_t ws_size,
                              hipStream_t stream) {
    const float* x     = (const float*)d_in[0];
    const float* Wqkv  = (const float*)d_in[1];
    const float* bqkv  = (const float*)d_in[2];
    const float* Wproj = (const float*)d_in[3];
    const float* bproj = (const float*)d_in[4];
    float* out = (float*)d_out;

    char* ws = (char*)d_ws;
    const size_t MB = 1024 * 1024;
    _Float16* Xh  = (_Float16*)(ws + 0 * MB);   // [4096][1024]   8 MB
    _Float16* Wqt = (_Float16*)(ws + 8 * MB);   // [3072][1024]   6 MB
    _Float16* Wpt = (_Float16*)(ws + 14 * MB);  // [1024][1024]   2 MB
    _Float16* Qg  = (_Float16*)(ws + 16 * MB);  // [32][2048][64] 8 MB (pre-scaled)
    _Float16* Kg  = (_Float16*)(ws + 24 * MB);  // [32][2048][64] 8 MB
    _Float16* Vtg = (_Float16*)(ws + 32 * MB);  // [32][64][2048] 8 MB (sigma cols)
    _Float16* AO  = (_Float16*)(ws + 40 * MB);  // [4096][1024]   8 MB

    prep_kernel<<<8192, 256, 0, stream>>>(x, Wqkv, Wproj, Xh, Wqt, Wpt);
    gemm_qkv<<<192, 512, 0, stream>>>(Xh, Wqt, bqkv, Qg, Kg, Vtg);
    attn_kernel<<<dim3(32, 16), 512, 0, stream>>>(Qg, Kg, Vtg, AO);
    gemm_proj<<<dim3(8, 64), 256, 0, stream>>>(AO, Wpt, bproj, out);
}